// Round 2
// baseline (1128.505 us; speedup 1.0000x reference)
//
#include <hip/hip_runtime.h>
#include <math.h>

// MambaBlock: B=4, L=1024, D_MODEL=512, D_INNER=1024, D_STATE=16, D_CONV=4, DT_RANK=32
// All inputs/outputs are float32 (per reference setup_inputs / return dtype).
#define B_   4
#define L_   1024
#define DM   512
#define DI   1024
#define NS   16
#define XDC  64      // DT_RANK + 2*D_STATE
#define BL   4096    // B_*L_

// C[M,N] = A[M,K] (row stride lda) * W[N,K]^T, fp32 accumulate.
// epi: 0 = none; 1 = softplus(v + bias[n]); 2 = v + resid[m*N+n]
__global__ __launch_bounds__(256) void gemm_tn(const float* __restrict__ A,
        const float* __restrict__ W, float* __restrict__ C,
        int M, int N, int K, int lda,
        int epi, const float* __restrict__ bias, const float* __restrict__ resid)
{
    __shared__ float As[16][68];
    __shared__ float Ws[16][68];
    const int tx = threadIdx.x & 15, ty = threadIdx.x >> 4;
    const int n0 = blockIdx.x * 64, m0 = blockIdx.y * 64;
    float acc[4][4] = {};

    for (int k0 = 0; k0 < K; k0 += 16) {
        #pragma unroll
        for (int j = 0; j < 4; j++) {
            int idx = threadIdx.x * 4 + j;      // 0..1023 over the 64x16 tile
            int r = idx >> 4, c = idx & 15;
            As[c][r] = A[(size_t)(m0 + r) * lda + k0 + c];
            Ws[c][r] = W[(size_t)(n0 + r) * K + k0 + c];
        }
        __syncthreads();
        #pragma unroll
        for (int kk = 0; kk < 16; kk++) {
            float a[4], b[4];
            #pragma unroll
            for (int i = 0; i < 4; i++) a[i] = As[kk][ty * 4 + i];
            #pragma unroll
            for (int j = 0; j < 4; j++) b[j] = Ws[kk][tx * 4 + j];
            #pragma unroll
            for (int i = 0; i < 4; i++)
                #pragma unroll
                for (int j = 0; j < 4; j++)
                    acc[i][j] = fmaf(a[i], b[j], acc[i][j]);
        }
        __syncthreads();
    }

    #pragma unroll
    for (int i = 0; i < 4; i++) {
        int m = m0 + ty * 4 + i;
        #pragma unroll
        for (int j = 0; j < 4; j++) {
            int n = n0 + tx * 4 + j;
            float v = acc[i][j];
            if (epi == 1) {
                v += bias[n];
                v = (v > 20.f) ? v : log1pf(__expf(v));   // softplus
            } else if (epi == 2) {
                v += resid[(size_t)m * N + n];
            }
            C[(size_t)m * N + n] = v;
        }
    }
}

// depthwise causal conv (k=4) + bias + SiLU.  xz row stride 2048, xs = cols [0,1024)
__global__ __launch_bounds__(256) void conv_silu(const float* __restrict__ xz,
        const float* __restrict__ cw, const float* __restrict__ cb,
        float* __restrict__ u)
{
    int idx = blockIdx.x * 256 + threadIdx.x;   // b*L*DI + l*DI + d
    int d  = idx & (DI - 1);
    int bl = idx >> 10;                          // b*L + l
    int l  = bl & (L_ - 1);
    float acc = cb[d];
    #pragma unroll
    for (int k = 0; k < 4; k++) {
        int ls = l - 3 + k;
        if (ls >= 0)
            acc = fmaf(xz[(size_t)(bl - 3 + k) * 2048 + d], cw[d * 4 + k], acc);
    }
    u[idx] = acc / (1.f + __expf(-acc));         // SiLU
}

// selective scan: one lane per (b, d, n); 16-lane shuffle reduce over n.
// Fuses the y * silu(z) gate on the writer lane.
__global__ __launch_bounds__(256) void scan_kernel(const float* __restrict__ delta,
        const float* __restrict__ u, const float* __restrict__ xdbl,
        const float* __restrict__ xz, const float* __restrict__ A_log,
        const float* __restrict__ Dp, float* __restrict__ y)
{
    int t = blockIdx.x * 256 + threadIdx.x;
    int n = t & 15;
    int g = t >> 4;             // (b,d) group
    int d = g & (DI - 1);
    int b = g >> 10;

    float Acoef = -__expf(A_log[d * NS + n]);
    float Dd = Dp[d];
    float h = 0.f;

    const size_t base_du = (size_t)b * L_ * DI + d;
    const size_t base_x  = (size_t)b * L_ * XDC;

    for (int l = 0; l < L_; l++) {
        float dv = delta[base_du + (size_t)l * DI];
        float uv = u[base_du + (size_t)l * DI];
        float Bn = xdbl[base_x + (size_t)l * XDC + 32 + n];
        float Cn = xdbl[base_x + (size_t)l * XDC + 48 + n];
        float dA = __expf(dv * Acoef);
        h = fmaf(dA, h, dv * uv * Bn);
        float p = h * Cn;
        p += __shfl_xor(p, 1);
        p += __shfl_xor(p, 2);
        p += __shfl_xor(p, 4);
        p += __shfl_xor(p, 8);
        if (n == 0) {
            float yv = p + uv * Dd;
            float zv = xz[(size_t)(b * L_ + l) * 2048 + DI + d];
            yv *= zv / (1.f + __expf(-zv));      // * silu(z)
            y[base_du + (size_t)l * DI] = yv;
        }
    }
}

// LayerNorm over last dim (512), one block per row, fp32 out.
__global__ __launch_bounds__(256) void ln_kernel(const float* __restrict__ r,
        const float* __restrict__ lnw, const float* __restrict__ lnb,
        float* __restrict__ out)
{
    int row = blockIdx.x;
    const float* rr = r + (size_t)row * DM;
    float v0 = rr[threadIdx.x], v1 = rr[threadIdx.x + 256];
    float s = v0 + v1, s2 = v0 * v0 + v1 * v1;
    #pragma unroll
    for (int off = 32; off > 0; off >>= 1) {
        s  += __shfl_down(s, off);
        s2 += __shfl_down(s2, off);
    }
    __shared__ float ls[4], ls2[4];
    __shared__ float mu_s, rstd_s;
    int wid = threadIdx.x >> 6, lane = threadIdx.x & 63;
    if (lane == 0) { ls[wid] = s; ls2[wid] = s2; }
    __syncthreads();
    if (threadIdx.x == 0) {
        float S = ls[0] + ls[1] + ls[2] + ls[3];
        float S2 = ls2[0] + ls2[1] + ls2[2] + ls2[3];
        float mu = S * (1.f / DM);
        float var = S2 * (1.f / DM) - mu * mu;
        mu_s = mu;
        rstd_s = rsqrtf(var + 1e-5f);
    }
    __syncthreads();
    float mu = mu_s, rstd = rstd_s;
    out[(size_t)row * DM + threadIdx.x] =
        (v0 - mu) * rstd * lnw[threadIdx.x] + lnb[threadIdx.x];
    out[(size_t)row * DM + threadIdx.x + 256] =
        (v1 - mu) * rstd * lnw[threadIdx.x + 256] + lnb[threadIdx.x + 256];
}

extern "C" void kernel_launch(void* const* d_in, const int* in_sizes, int n_in,
                              void* d_out, int out_size, void* d_ws, size_t ws_size,
                              hipStream_t stream)
{
    const float* x         = (const float*)d_in[0];
    const float* in_proj_w = (const float*)d_in[1];
    const float* conv_w    = (const float*)d_in[2];
    const float* conv_b    = (const float*)d_in[3];
    const float* x_proj_w  = (const float*)d_in[4];
    const float* dt_proj_w = (const float*)d_in[5];
    const float* dt_proj_b = (const float*)d_in[6];
    const float* A_log     = (const float*)d_in[7];
    const float* Dvec      = (const float*)d_in[8];
    const float* out_proj_w= (const float*)d_in[9];
    const float* ln_w      = (const float*)d_in[10];
    const float* ln_b      = (const float*)d_in[11];
    float* out = (float*)d_out;

    float* ws    = (float*)d_ws;
    float* xz    = ws;                                  // 4096 x 2048
    float* u     = xz    + (size_t)BL * 2048;           // 4096 x 1024
    float* xdbl  = u     + (size_t)BL * DI;             // 4096 x 64
    float* delta = xdbl  + (size_t)BL * XDC;            // 4096 x 1024
    float* y     = delta + (size_t)BL * DI;             // 4096 x 1024
    float* r     = y     + (size_t)BL * DI;             // 4096 x 512

    dim3 blk(256);

    // 1) xz = x @ in_proj_w^T          (4096 x 2048, K=512)
    gemm_tn<<<dim3(2048 / 64, BL / 64), blk, 0, stream>>>(
        x, in_proj_w, xz, BL, 2048, DM, DM, 0, nullptr, nullptr);

    // 2) u = silu(causal_conv(xs) + cb)
    conv_silu<<<(BL * DI) / 256, blk, 0, stream>>>(xz, conv_w, conv_b, u);

    // 3) x_dbl = u @ x_proj_w^T        (4096 x 64, K=1024)
    gemm_tn<<<dim3(XDC / 64, BL / 64), blk, 0, stream>>>(
        u, x_proj_w, xdbl, BL, XDC, DI, DI, 0, nullptr, nullptr);

    // 4) delta = softplus(dt @ dt_proj_w^T + b)   (4096 x 1024, K=32, lda=64)
    gemm_tn<<<dim3(DI / 64, BL / 64), blk, 0, stream>>>(
        xdbl, dt_proj_w, delta, BL, DI, 32, XDC, 1, dt_proj_b, nullptr);

    // 5) selective scan + gate
    scan_kernel<<<(BL * NS) / 256, blk, 0, stream>>>(
        delta, u, xdbl, xz, A_log, Dvec, y);

    // 6) r = y @ out_proj_w^T + x      (4096 x 512, K=1024)
    gemm_tn<<<dim3(DM / 64, BL / 64), blk, 0, stream>>>(
        y, out_proj_w, r, BL, DM, DI, DI, 2, nullptr, x);

    // 7) LayerNorm -> fp32 out
    ln_kernel<<<BL, blk, 0, stream>>>(r, ln_w, ln_b, out);
}

// Round 3
// 621.264 us; speedup vs baseline: 1.8165x; 1.8165x over previous
//
#include <hip/hip_runtime.h>
#include <math.h>

// MambaBlock: B=4, L=1024, D_MODEL=512, D_INNER=1024, D_STATE=16, D_CONV=4, DT_RANK=32
// All inputs/outputs are float32.
#define B_   4
#define L_   1024
#define DM   512
#define DI   1024
#define NS   16
#define XDC  64      // DT_RANK + 2*D_STATE
#define BL   4096    // B_*L_

// C[M,N] = A[M,K] (row stride lda) * W[N,K]^T, fp32 accumulate.
// epi: 0 = none; 1 = softplus(v + bias[n]); 2 = v + resid[m*N+n]
__global__ __launch_bounds__(256) void gemm_tn(const float* __restrict__ A,
        const float* __restrict__ W, float* __restrict__ C,
        int M, int N, int K, int lda,
        int epi, const float* __restrict__ bias, const float* __restrict__ resid)
{
    __shared__ float As[16][68];
    __shared__ float Ws[16][68];
    const int tx = threadIdx.x & 15, ty = threadIdx.x >> 4;
    const int n0 = blockIdx.x * 64, m0 = blockIdx.y * 64;
    float acc[4][4] = {};

    for (int k0 = 0; k0 < K; k0 += 16) {
        #pragma unroll
        for (int j = 0; j < 4; j++) {
            int idx = threadIdx.x * 4 + j;      // 0..1023 over the 64x16 tile
            int r = idx >> 4, c = idx & 15;
            As[c][r] = A[(size_t)(m0 + r) * lda + k0 + c];
            Ws[c][r] = W[(size_t)(n0 + r) * K + k0 + c];
        }
        __syncthreads();
        #pragma unroll
        for (int kk = 0; kk < 16; kk++) {
            float a[4], b[4];
            #pragma unroll
            for (int i = 0; i < 4; i++) a[i] = As[kk][ty * 4 + i];
            #pragma unroll
            for (int j = 0; j < 4; j++) b[j] = Ws[kk][tx * 4 + j];
            #pragma unroll
            for (int i = 0; i < 4; i++)
                #pragma unroll
                for (int j = 0; j < 4; j++)
                    acc[i][j] = fmaf(a[i], b[j], acc[i][j]);
        }
        __syncthreads();
    }

    #pragma unroll
    for (int i = 0; i < 4; i++) {
        int m = m0 + ty * 4 + i;
        #pragma unroll
        for (int j = 0; j < 4; j++) {
            int n = n0 + tx * 4 + j;
            float v = acc[i][j];
            if (epi == 1) {
                v += bias[n];
                v = (v > 20.f) ? v : log1pf(__expf(v));   // softplus
            } else if (epi == 2) {
                v += resid[(size_t)m * N + n];
            }
            C[(size_t)m * N + n] = v;
        }
    }
}

// depthwise causal conv (k=4) + bias + SiLU.  xz row stride 2048, xs = cols [0,1024)
__global__ __launch_bounds__(256) void conv_silu(const float* __restrict__ xz,
        const float* __restrict__ cw, const float* __restrict__ cb,
        float* __restrict__ u)
{
    int idx = blockIdx.x * 256 + threadIdx.x;   // b*L*DI + l*DI + d
    int d  = idx & (DI - 1);
    int bl = idx >> 10;                          // b*L + l
    int l  = bl & (L_ - 1);
    float acc = cb[d];
    #pragma unroll
    for (int k = 0; k < 4; k++) {
        int ls = l - 3 + k;
        if (ls >= 0)
            acc = fmaf(xz[(size_t)(bl - 3 + k) * 2048 + d], cw[d * 4 + k], acc);
    }
    u[idx] = acc / (1.f + __expf(-acc));         // SiLU
}

// selective scan, time-register-blocked: one lane per (b, d, n).
// Per 16-step chunk: lane n prefetches timestep l0+n of delta/u/z (shfl-broadcast
// later), and 16 B + 16 C values for its own n. All chunk loads are independent ->
// a single latency window per 16 steps. Inner loop is pure VALU/shfl; the only
// loop-carried dependence is the fmaf into h.
__global__ __launch_bounds__(256) void scan_kernel(const float* __restrict__ delta,
        const float* __restrict__ u, const float* __restrict__ xdbl,
        const float* __restrict__ xz, const float* __restrict__ A_log,
        const float* __restrict__ Dp, float* __restrict__ y)
{
    const int t = blockIdx.x * 256 + threadIdx.x;
    const int n = t & 15;
    const int g = t >> 4;             // (b,d) group
    const int d = g & (DI - 1);
    const int b = g >> 10;
    const int lane = threadIdx.x & 63;
    const int grpbase = lane & 48;    // group's base lane within the wave

    const float Acoef = -__expf(A_log[d * NS + n]);
    const float Dd = Dp[d];
    float h = 0.f;

    const size_t base_du = (size_t)b * L_ * DI + d;
    const size_t base_x  = (size_t)b * L_ * XDC;
    const size_t base_z  = (size_t)b * L_ * 2048 + DI + d;

    for (int l0 = 0; l0 < L_; l0 += 16) {
        // lane n holds timestep l0+n of delta / u / z for this (b,d)
        float dvec = delta[base_du + (size_t)(l0 + n) * DI];
        float uvec = u    [base_du + (size_t)(l0 + n) * DI];
        float zvec = xz   [base_z  + (size_t)(l0 + n) * 2048];
        float Bv[16], Cv[16];
        #pragma unroll
        for (int j = 0; j < 16; j++) {
            Bv[j] = xdbl[base_x + (size_t)(l0 + j) * XDC + 32 + n];
            Cv[j] = xdbl[base_x + (size_t)(l0 + j) * XDC + 48 + n];
        }

        #pragma unroll
        for (int j = 0; j < 16; j++) {
            float dv = __shfl(dvec, grpbase + j);
            float uv = __shfl(uvec, grpbase + j);
            float zv = __shfl(zvec, grpbase + j);
            float dA = __expf(dv * Acoef);
            h = fmaf(dA, h, dv * uv * Bv[j]);
            float p = h * Cv[j];
            p += __shfl_xor(p, 1);
            p += __shfl_xor(p, 2);
            p += __shfl_xor(p, 4);
            p += __shfl_xor(p, 8);
            if (n == 0) {
                float yv = p + uv * Dd;
                yv *= zv / (1.f + __expf(-zv));      // * silu(z)
                y[base_du + (size_t)(l0 + j) * DI] = yv;
            }
        }
    }
}

// LayerNorm over last dim (512), one block per row, fp32 out.
__global__ __launch_bounds__(256) void ln_kernel(const float* __restrict__ r,
        const float* __restrict__ lnw, const float* __restrict__ lnb,
        float* __restrict__ out)
{
    int row = blockIdx.x;
    const float* rr = r + (size_t)row * DM;
    float v0 = rr[threadIdx.x], v1 = rr[threadIdx.x + 256];
    float s = v0 + v1, s2 = v0 * v0 + v1 * v1;
    #pragma unroll
    for (int off = 32; off > 0; off >>= 1) {
        s  += __shfl_down(s, off);
        s2 += __shfl_down(s2, off);
    }
    __shared__ float ls[4], ls2[4];
    __shared__ float mu_s, rstd_s;
    int wid = threadIdx.x >> 6, lane = threadIdx.x & 63;
    if (lane == 0) { ls[wid] = s; ls2[wid] = s2; }
    __syncthreads();
    if (threadIdx.x == 0) {
        float S = ls[0] + ls[1] + ls[2] + ls[3];
        float S2 = ls2[0] + ls2[1] + ls2[2] + ls2[3];
        float mu = S * (1.f / DM);
        float var = S2 * (1.f / DM) - mu * mu;
        mu_s = mu;
        rstd_s = rsqrtf(var + 1e-5f);
    }
    __syncthreads();
    float mu = mu_s, rstd = rstd_s;
    out[(size_t)row * DM + threadIdx.x] =
        (v0 - mu) * rstd * lnw[threadIdx.x] + lnb[threadIdx.x];
    out[(size_t)row * DM + threadIdx.x + 256] =
        (v1 - mu) * rstd * lnw[threadIdx.x + 256] + lnb[threadIdx.x + 256];
}

extern "C" void kernel_launch(void* const* d_in, const int* in_sizes, int n_in,
                              void* d_out, int out_size, void* d_ws, size_t ws_size,
                              hipStream_t stream)
{
    const float* x         = (const float*)d_in[0];
    const float* in_proj_w = (const float*)d_in[1];
    const float* conv_w    = (const float*)d_in[2];
    const float* conv_b    = (const float*)d_in[3];
    const float* x_proj_w  = (const float*)d_in[4];
    const float* dt_proj_w = (const float*)d_in[5];
    const float* dt_proj_b = (const float*)d_in[6];
    const float* A_log     = (const float*)d_in[7];
    const float* Dvec      = (const float*)d_in[8];
    const float* out_proj_w= (const float*)d_in[9];
    const float* ln_w      = (const float*)d_in[10];
    const float* ln_b      = (const float*)d_in[11];
    float* out = (float*)d_out;

    float* ws    = (float*)d_ws;
    float* xz    = ws;                                  // 4096 x 2048
    float* u     = xz    + (size_t)BL * 2048;           // 4096 x 1024
    float* xdbl  = u     + (size_t)BL * DI;             // 4096 x 64
    float* delta = xdbl  + (size_t)BL * XDC;            // 4096 x 1024
    float* y     = delta + (size_t)BL * DI;             // 4096 x 1024
    float* r     = y     + (size_t)BL * DI;             // 4096 x 512

    dim3 blk(256);

    // 1) xz = x @ in_proj_w^T          (4096 x 2048, K=512)
    gemm_tn<<<dim3(2048 / 64, BL / 64), blk, 0, stream>>>(
        x, in_proj_w, xz, BL, 2048, DM, DM, 0, nullptr, nullptr);

    // 2) u = silu(causal_conv(xs) + cb)
    conv_silu<<<(BL * DI) / 256, blk, 0, stream>>>(xz, conv_w, conv_b, u);

    // 3) x_dbl = u @ x_proj_w^T        (4096 x 64, K=1024)
    gemm_tn<<<dim3(XDC / 64, BL / 64), blk, 0, stream>>>(
        u, x_proj_w, xdbl, BL, XDC, DI, DI, 0, nullptr, nullptr);

    // 4) delta = softplus(dt @ dt_proj_w^T + b)   (4096 x 1024, K=32, lda=64)
    gemm_tn<<<dim3(DI / 64, BL / 64), blk, 0, stream>>>(
        xdbl, dt_proj_w, delta, BL, DI, 32, XDC, 1, dt_proj_b, nullptr);

    // 5) selective scan + gate
    scan_kernel<<<(BL * NS) / 256, blk, 0, stream>>>(
        delta, u, xdbl, xz, A_log, Dvec, y);

    // 6) r = y @ out_proj_w^T + x      (4096 x 512, K=1024)
    gemm_tn<<<dim3(DM / 64, BL / 64), blk, 0, stream>>>(
        y, out_proj_w, r, BL, DM, DI, DI, 2, nullptr, x);

    // 7) LayerNorm -> fp32 out
    ln_kernel<<<BL, blk, 0, stream>>>(r, ln_w, ln_b, out);
}

// Round 4
// 564.506 us; speedup vs baseline: 1.9991x; 1.1005x over previous
//
#include <hip/hip_runtime.h>
#include <math.h>

// MambaBlock: B=4, L=1024, D_MODEL=512, D_INNER=1024, D_STATE=16, D_CONV=4, DT_RANK=32
// All inputs/outputs are float32.
#define B_   4
#define L_   1024
#define DM   512
#define DI   1024
#define NS   16
#define XDC  64      // DT_RANK + 2*D_STATE
#define BL   4096    // B_*L_

// C[M,N] = A[M,K] (row stride lda) * W[N,K]^T, fp32 accumulate.
// 128x64 tile, 8x4 per thread, float4 global loads, transposed LDS store.
// epi: 0 = none; 1 = softplus(v + bias[n]); 2 = v + resid[m*N+n]
__global__ __launch_bounds__(256) void gemm_tn(const float* __restrict__ A,
        const float* __restrict__ W, float* __restrict__ C,
        int M, int N, int K, int lda,
        int epi, const float* __restrict__ bias, const float* __restrict__ resid)
{
    __shared__ float As[16][132];   // [k][m], pad -> mostly 2-way on store
    __shared__ float Ws[16][68];    // [k][n]
    const int tid = threadIdx.x;
    const int tx = tid & 15, ty = tid >> 4;
    const int n0 = blockIdx.x * 64, m0 = blockIdx.y * 128;
    float acc[8][4] = {};

    for (int k0 = 0; k0 < K; k0 += 16) {
        // A tile: 128 rows x 16 cols = 512 float4, 2 per thread
        #pragma unroll
        for (int i = 0; i < 2; i++) {
            int idx = tid * 2 + i;              // 0..511
            int r = idx >> 2, c4 = (idx & 3) * 4;
            const float4 v = *(const float4*)&A[(size_t)(m0 + r) * lda + k0 + c4];
            As[c4 + 0][r] = v.x; As[c4 + 1][r] = v.y;
            As[c4 + 2][r] = v.z; As[c4 + 3][r] = v.w;
        }
        // W tile: 64 rows x 16 cols = 256 float4, 1 per thread
        {
            int r = tid >> 2, c4 = (tid & 3) * 4;
            const float4 v = *(const float4*)&W[(size_t)(n0 + r) * K + k0 + c4];
            Ws[c4 + 0][r] = v.x; Ws[c4 + 1][r] = v.y;
            Ws[c4 + 2][r] = v.z; Ws[c4 + 3][r] = v.w;
        }
        __syncthreads();
        #pragma unroll
        for (int kk = 0; kk < 16; kk++) {
            float a[8], b[4];
            #pragma unroll
            for (int i = 0; i < 8; i++) a[i] = As[kk][ty * 8 + i];
            #pragma unroll
            for (int j = 0; j < 4; j++) b[j] = Ws[kk][tx * 4 + j];
            #pragma unroll
            for (int i = 0; i < 8; i++)
                #pragma unroll
                for (int j = 0; j < 4; j++)
                    acc[i][j] = fmaf(a[i], b[j], acc[i][j]);
        }
        __syncthreads();
    }

    #pragma unroll
    for (int i = 0; i < 8; i++) {
        int m = m0 + ty * 8 + i;
        int nb = n0 + tx * 4;
        float4 v = make_float4(acc[i][0], acc[i][1], acc[i][2], acc[i][3]);
        if (epi == 1) {
            v.x += bias[nb + 0]; v.y += bias[nb + 1];
            v.z += bias[nb + 2]; v.w += bias[nb + 3];
            v.x = (v.x > 20.f) ? v.x : log1pf(__expf(v.x));
            v.y = (v.y > 20.f) ? v.y : log1pf(__expf(v.y));
            v.z = (v.z > 20.f) ? v.z : log1pf(__expf(v.z));
            v.w = (v.w > 20.f) ? v.w : log1pf(__expf(v.w));
        } else if (epi == 2) {
            const float4 rv = *(const float4*)&resid[(size_t)m * N + nb];
            v.x += rv.x; v.y += rv.y; v.z += rv.z; v.w += rv.w;
        }
        *(float4*)&C[(size_t)m * N + nb] = v;
    }
}

// depthwise causal conv (k=4) + bias + SiLU.  xz row stride 2048, xs = cols [0,1024)
__global__ __launch_bounds__(256) void conv_silu(const float* __restrict__ xz,
        const float* __restrict__ cw, const float* __restrict__ cb,
        float* __restrict__ u)
{
    int idx = blockIdx.x * 256 + threadIdx.x;   // b*L*DI + l*DI + d
    int d  = idx & (DI - 1);
    int bl = idx >> 10;                          // b*L + l
    int l  = bl & (L_ - 1);
    float acc = cb[d];
    #pragma unroll
    for (int k = 0; k < 4; k++) {
        int ls = l - 3 + k;
        if (ls >= 0)
            acc = fmaf(xz[(size_t)(bl - 3 + k) * 2048 + d], cw[d * 4 + k], acc);
    }
    u[idx] = acc / (1.f + __expf(-acc));         // SiLU
}

// selective scan, chunked: one lane per (b, d, n), 16-step chunks.
// Per chunk: all loads (redundant delta/u across the group -> L1 broadcast),
// all exps and dBu products are hoisted off the recurrence; the only serial
// chain is 16 dependent fmafs. shfl_xor reductions batched at chunk end
// (16 independent trees -> pipelined).
__global__ __launch_bounds__(256) void scan_kernel(const float* __restrict__ delta,
        const float* __restrict__ u, const float* __restrict__ xdbl,
        const float* __restrict__ xz, const float* __restrict__ A_log,
        const float* __restrict__ Dp, float* __restrict__ y)
{
    const int t = blockIdx.x * 256 + threadIdx.x;
    const int n = t & 15;
    const int g = t >> 4;             // (b,d) group
    const int d = g & (DI - 1);
    const int b = g >> 10;

    const float Acoef = -__expf(A_log[d * NS + n]);
    const float Dd = Dp[d];
    float h = 0.f;

    const size_t base_du = (size_t)b * L_ * DI + d;
    const size_t base_x  = (size_t)b * L_ * XDC;
    const size_t base_z  = (size_t)b * L_ * 2048 + DI + d;

    for (int l0 = 0; l0 < L_; l0 += 16) {
        float dv[16], uv[16], Bv[16], Cv[16];
        #pragma unroll
        for (int j = 0; j < 16; j++) {
            dv[j] = delta[base_du + (size_t)(l0 + j) * DI];
            uv[j] = u    [base_du + (size_t)(l0 + j) * DI];
            Bv[j] = xdbl[base_x + (size_t)(l0 + j) * XDC + 32 + n];
            Cv[j] = xdbl[base_x + (size_t)(l0 + j) * XDC + 48 + n];
        }
        float zv[16];
        if (n == 0) {
            #pragma unroll
            for (int j = 0; j < 16; j++)
                zv[j] = xz[base_z + (size_t)(l0 + j) * 2048];
        }

        // hoist: Bv <- dBu = delta*u*B ; dv <- dA = exp(delta*Acoef)
        #pragma unroll
        for (int j = 0; j < 16; j++) {
            Bv[j] *= dv[j] * uv[j];
            dv[j] = __expf(dv[j] * Acoef);
        }

        // serial recurrence: only dependent chain is the fmaf into h
        float p[16];
        #pragma unroll
        for (int j = 0; j < 16; j++) {
            h = fmaf(dv[j], h, Bv[j]);
            p[j] = h * Cv[j];
        }

        // batched 16-lane reductions, level-by-level for pipelining
        #pragma unroll
        for (int m = 1; m <= 8; m <<= 1) {
            #pragma unroll
            for (int j = 0; j < 16; j++)
                p[j] += __shfl_xor(p[j], m);
        }

        if (n == 0) {
            #pragma unroll
            for (int j = 0; j < 16; j++) {
                float yv = p[j] + uv[j] * Dd;
                yv *= zv[j] / (1.f + __expf(-zv[j]));      // * silu(z)
                y[base_du + (size_t)(l0 + j) * DI] = yv;
            }
        }
    }
}

// LayerNorm over last dim (512), one block per row, fp32 out.
__global__ __launch_bounds__(256) void ln_kernel(const float* __restrict__ r,
        const float* __restrict__ lnw, const float* __restrict__ lnb,
        float* __restrict__ out)
{
    int row = blockIdx.x;
    const float* rr = r + (size_t)row * DM;
    float v0 = rr[threadIdx.x], v1 = rr[threadIdx.x + 256];
    float s = v0 + v1, s2 = v0 * v0 + v1 * v1;
    #pragma unroll
    for (int off = 32; off > 0; off >>= 1) {
        s  += __shfl_down(s, off);
        s2 += __shfl_down(s2, off);
    }
    __shared__ float ls[4], ls2[4];
    __shared__ float mu_s, rstd_s;
    int wid = threadIdx.x >> 6, lane = threadIdx.x & 63;
    if (lane == 0) { ls[wid] = s; ls2[wid] = s2; }
    __syncthreads();
    if (threadIdx.x == 0) {
        float S = ls[0] + ls[1] + ls[2] + ls[3];
        float S2 = ls2[0] + ls2[1] + ls2[2] + ls2[3];
        float mu = S * (1.f / DM);
        float var = S2 * (1.f / DM) - mu * mu;
        mu_s = mu;
        rstd_s = rsqrtf(var + 1e-5f);
    }
    __syncthreads();
    float mu = mu_s, rstd = rstd_s;
    out[(size_t)row * DM + threadIdx.x] =
        (v0 - mu) * rstd * lnw[threadIdx.x] + lnb[threadIdx.x];
    out[(size_t)row * DM + threadIdx.x + 256] =
        (v1 - mu) * rstd * lnw[threadIdx.x + 256] + lnb[threadIdx.x + 256];
}

extern "C" void kernel_launch(void* const* d_in, const int* in_sizes, int n_in,
                              void* d_out, int out_size, void* d_ws, size_t ws_size,
                              hipStream_t stream)
{
    const float* x         = (const float*)d_in[0];
    const float* in_proj_w = (const float*)d_in[1];
    const float* conv_w    = (const float*)d_in[2];
    const float* conv_b    = (const float*)d_in[3];
    const float* x_proj_w  = (const float*)d_in[4];
    const float* dt_proj_w = (const float*)d_in[5];
    const float* dt_proj_b = (const float*)d_in[6];
    const float* A_log     = (const float*)d_in[7];
    const float* Dvec      = (const float*)d_in[8];
    const float* out_proj_w= (const float*)d_in[9];
    const float* ln_w      = (const float*)d_in[10];
    const float* ln_b      = (const float*)d_in[11];
    float* out = (float*)d_out;

    float* ws    = (float*)d_ws;
    float* xz    = ws;                                  // 4096 x 2048
    float* u     = xz    + (size_t)BL * 2048;           // 4096 x 1024
    float* xdbl  = u     + (size_t)BL * DI;             // 4096 x 64
    float* delta = xdbl  + (size_t)BL * XDC;            // 4096 x 1024
    float* y     = delta + (size_t)BL * DI;             // 4096 x 1024
    float* r     = y     + (size_t)BL * DI;             // 4096 x 512

    dim3 blk(256);

    // 1) xz = x @ in_proj_w^T          (4096 x 2048, K=512)
    gemm_tn<<<dim3(2048 / 64, BL / 128), blk, 0, stream>>>(
        x, in_proj_w, xz, BL, 2048, DM, DM, 0, nullptr, nullptr);

    // 2) u = silu(causal_conv(xs) + cb)
    conv_silu<<<(BL * DI) / 256, blk, 0, stream>>>(xz, conv_w, conv_b, u);

    // 3) x_dbl = u @ x_proj_w^T        (4096 x 64, K=1024)
    gemm_tn<<<dim3(XDC / 64, BL / 128), blk, 0, stream>>>(
        u, x_proj_w, xdbl, BL, XDC, DI, DI, 0, nullptr, nullptr);

    // 4) delta = softplus(dt @ dt_proj_w^T + b)   (4096 x 1024, K=32, lda=64)
    gemm_tn<<<dim3(DI / 64, BL / 128), blk, 0, stream>>>(
        xdbl, dt_proj_w, delta, BL, DI, 32, XDC, 1, dt_proj_b, nullptr);

    // 5) selective scan + gate
    scan_kernel<<<(BL * NS) / 256, blk, 0, stream>>>(
        delta, u, xdbl, xz, A_log, Dvec, y);

    // 6) r = y @ out_proj_w^T + x      (4096 x 512, K=1024)
    gemm_tn<<<dim3(DM / 64, BL / 128), blk, 0, stream>>>(
        y, out_proj_w, r, BL, DM, DI, DI, 2, nullptr, x);

    // 7) LayerNorm -> fp32 out
    ln_kernel<<<BL, blk, 0, stream>>>(r, ln_w, ln_b, out);
}